// Round 1
// baseline (8106.338 us; speedup 1.0000x reference)
//
#include <hip/hip_runtime.h>
#include <hip/hip_bf16.h>
#include <math.h>

// Problem dims
static constexpr int NB = 1024;  // batch
static constexpr int NT = 40;    // seq len
static constexpr int NE = 512;   // embed dim
static constexpr int NH = 1024;  // hidden
static constexpr int NL = 256;   // latent out
static constexpr int NA = 2048;  // feature dim

// GEMM tile
static constexpr int BM = 64, BN = 64, BKT = 16;

// ---------------------------------------------------------------------------
// scale[r] = g[r] / ||v[r,:]||   (weight_norm dim=0 on [out,in])
__global__ __launch_bounds__(256) void k_rowscale(const float* __restrict__ v,
                                                  const float* __restrict__ g,
                                                  float* __restrict__ scale,
                                                  int cols) {
    int r = blockIdx.x;
    const float* vr = v + (size_t)r * cols;
    float s = 0.f;
    for (int k = threadIdx.x; k < cols; k += 256) {
        float x = vr[k];
        s += x * x;
    }
    __shared__ float red[256];
    red[threadIdx.x] = s;
    __syncthreads();
    for (int o = 128; o > 0; o >>= 1) {
        if (threadIdx.x < o) red[threadIdx.x] += red[threadIdx.x + o];
        __syncthreads();
    }
    if (threadIdx.x == 0) scale[r] = g[r] * rsqrtf(red[0]);
}

// ---------------------------------------------------------------------------
// C[m,n] = (sum_k A[m,k]*B[n,k]) * scale[n] + bias[n]
// A: [M,lda] row-major, B: [N,ldb] row-major (NT gemm). M,N multiples of 64,
// K multiple of 16, lda/ldb multiples of 4 (float4 loads).
__global__ __launch_bounds__(256) void k_gemm_nt(
    const float* __restrict__ A, int lda,
    const float* __restrict__ Bm, int ldb,
    float* __restrict__ C, int ldc, int K,
    const float* __restrict__ scale,
    const float* __restrict__ bias) {
    __shared__ float As[BKT][BM + 4];
    __shared__ float Bs[BKT][BN + 4];
    const int tid = threadIdx.x;
    const int row = tid >> 2;         // 0..63
    const int k0 = (tid & 3) << 2;    // 0,4,8,12
    const int ty = tid >> 4, tx = tid & 15;
    const float* Ap = A + (size_t)(blockIdx.y * BM + row) * lda + k0;
    const float* Bp = Bm + (size_t)(blockIdx.x * BN + row) * ldb + k0;
    float acc[4][4] = {};
    for (int kt = 0; kt < K; kt += BKT) {
        float4 av = *reinterpret_cast<const float4*>(Ap + kt);
        float4 bv = *reinterpret_cast<const float4*>(Bp + kt);
        As[k0 + 0][row] = av.x; As[k0 + 1][row] = av.y;
        As[k0 + 2][row] = av.z; As[k0 + 3][row] = av.w;
        Bs[k0 + 0][row] = bv.x; Bs[k0 + 1][row] = bv.y;
        Bs[k0 + 2][row] = bv.z; Bs[k0 + 3][row] = bv.w;
        __syncthreads();
#pragma unroll
        for (int k = 0; k < BKT; ++k) {
            float a[4], b[4];
            *reinterpret_cast<float4*>(a) = *reinterpret_cast<const float4*>(&As[k][ty << 2]);
            *reinterpret_cast<float4*>(b) = *reinterpret_cast<const float4*>(&Bs[k][tx << 2]);
#pragma unroll
            for (int i = 0; i < 4; ++i)
#pragma unroll
                for (int j = 0; j < 4; ++j)
                    acc[i][j] = fmaf(a[i], b[j], acc[i][j]);
        }
        __syncthreads();
    }
    const int gm0 = blockIdx.y * BM + (ty << 2);
    const int gn0 = blockIdx.x * BN + (tx << 2);
#pragma unroll
    for (int i = 0; i < 4; ++i) {
#pragma unroll
        for (int j = 0; j < 4; ++j) {
            int gn = gn0 + j;
            float x = acc[i][j];
            if (scale) x *= scale[gn];
            if (bias) x += bias[gn];
            C[(size_t)(gm0 + i) * ldc + gn] = x;
        }
    }
}

// ---------------------------------------------------------------------------
// gates[b,n] = b_ih[n]+b_hh[n] + sum_k embed[cap[b,t],k]*W_ih[n,k]
//                               + sum_k h[b,k]*W_hh[n,k]
__global__ __launch_bounds__(256) void k_lstm_gates(
    const int* __restrict__ cap,
    const float* __restrict__ embed,
    const float* __restrict__ h,
    const float* __restrict__ Wih,
    const float* __restrict__ Whh,
    const float* __restrict__ bih,
    const float* __restrict__ bhh,
    float* __restrict__ gates, int t) {
    __shared__ float As[BKT][BM + 4];
    __shared__ float Bs[BKT][BN + 4];
    __shared__ int cidx[BM];
    const int tid = threadIdx.x;
    if (tid < BM) cidx[tid] = cap[(size_t)(blockIdx.y * BM + tid) * NT + t];
    __syncthreads();
    const int row = tid >> 2;
    const int k0 = (tid & 3) << 2;
    const int ty = tid >> 4, tx = tid & 15;
    const float* erow = embed + (size_t)cidx[row] * NE + k0;
    const float* hrow = h + (size_t)(blockIdx.y * BM + row) * NH + k0;
    const float* wirow = Wih + (size_t)(blockIdx.x * BN + row) * NE + k0;
    const float* whrow = Whh + (size_t)(blockIdx.x * BN + row) * NH + k0;
    float acc[4][4] = {};
    for (int kt = 0; kt < NE + NH; kt += BKT) {
        float4 av, bv;
        if (kt < NE) {
            av = *reinterpret_cast<const float4*>(erow + kt);
            bv = *reinterpret_cast<const float4*>(wirow + kt);
        } else {
            av = *reinterpret_cast<const float4*>(hrow + (kt - NE));
            bv = *reinterpret_cast<const float4*>(whrow + (kt - NE));
        }
        As[k0 + 0][row] = av.x; As[k0 + 1][row] = av.y;
        As[k0 + 2][row] = av.z; As[k0 + 3][row] = av.w;
        Bs[k0 + 0][row] = bv.x; Bs[k0 + 1][row] = bv.y;
        Bs[k0 + 2][row] = bv.z; Bs[k0 + 3][row] = bv.w;
        __syncthreads();
#pragma unroll
        for (int k = 0; k < BKT; ++k) {
            float a[4], b[4];
            *reinterpret_cast<float4*>(a) = *reinterpret_cast<const float4*>(&As[k][ty << 2]);
            *reinterpret_cast<float4*>(b) = *reinterpret_cast<const float4*>(&Bs[k][tx << 2]);
#pragma unroll
            for (int i = 0; i < 4; ++i)
#pragma unroll
                for (int j = 0; j < 4; ++j)
                    acc[i][j] = fmaf(a[i], b[j], acc[i][j]);
        }
        __syncthreads();
    }
    const int gm0 = blockIdx.y * BM + (ty << 2);
    const int gn0 = blockIdx.x * BN + (tx << 2);
#pragma unroll
    for (int i = 0; i < 4; ++i) {
#pragma unroll
        for (int j = 0; j < 4; ++j) {
            int gn = gn0 + j;
            gates[(size_t)(gm0 + i) * (4 * NH) + gn] = acc[i][j] + bih[gn] + bhh[gn];
        }
    }
}

// ---------------------------------------------------------------------------
__global__ __launch_bounds__(256) void k_lstm_update(
    const float* __restrict__ gates,
    float* __restrict__ h, float* __restrict__ c,
    const int* __restrict__ cap_len,
    float* __restrict__ h_last, int t) {
    int idx = blockIdx.x * 256 + threadIdx.x;   // 0 .. NB*NH-1
    int b = idx >> 10;        // / NH
    int j = idx & (NH - 1);
    const float* gr = gates + ((size_t)b << 12);  // b * 4H
    float gi = gr[j];
    float gf = gr[j + NH];
    float gg = gr[j + 2 * NH];
    float go = gr[j + 3 * NH];
    float si = 1.f / (1.f + __expf(-gi));
    float sf = 1.f / (1.f + __expf(-gf));
    float so = 1.f / (1.f + __expf(-go));
    float cn = sf * c[idx] + si * tanhf(gg);
    float hn = so * tanhf(cn);
    c[idx] = cn;
    h[idx] = hn;
    if (cap_len[b] == t + 1) h_last[idx] = hn;
}

// ---------------------------------------------------------------------------
extern "C" void kernel_launch(void* const* d_in, const int* in_sizes, int n_in,
                              void* d_out, int out_size, void* d_ws, size_t ws_size,
                              hipStream_t stream) {
    const int* cap      = (const int*)d_in[0];
    const int* cap_len  = (const int*)d_in[1];
    const float* feat   = (const float*)d_in[2];
    const float* embed  = (const float*)d_in[3];
    const float* W_ih   = (const float*)d_in[4];
    const float* W_hh   = (const float*)d_in[5];
    const float* b_ih   = (const float*)d_in[6];
    const float* b_hh   = (const float*)d_in[7];
    const float* v_ih0  = (const float*)d_in[8];
    const float* g_ih0  = (const float*)d_in[9];
    const float* b_ih0  = (const float*)d_in[10];
    const float* v_ic0  = (const float*)d_in[11];
    const float* g_ic0  = (const float*)d_in[12];
    const float* b_ic0  = (const float*)d_in[13];
    const float* v_mu   = (const float*)d_in[14];
    const float* g_mu   = (const float*)d_in[15];
    const float* b_mu   = (const float*)d_in[16];
    const float* v_s2   = (const float*)d_in[17];
    const float* g_s2   = (const float*)d_in[18];
    const float* b_s2   = (const float*)d_in[19];
    float* out = (float*)d_out;

    // workspace layout (floats)
    float* ws = (float*)d_ws;
    float* h      = ws;                                // NB*NH
    float* c      = h + (size_t)NB * NH;               // NB*NH
    float* h_last = c + (size_t)NB * NH;               // NB*NH
    float* gates  = h_last + (size_t)NB * NH;          // NB*4*NH
    float* sc_ih0 = gates + (size_t)NB * 4 * NH;       // NH
    float* sc_ic0 = sc_ih0 + NH;                       // NH
    float* sc_mu  = sc_ic0 + NH;                       // NL
    float* sc_s2  = sc_mu + NL;                        // NL

    dim3 blk(256);

    // weight-norm row scales
    k_rowscale<<<NH, blk, 0, stream>>>(v_ih0, g_ih0, sc_ih0, NA);
    k_rowscale<<<NH, blk, 0, stream>>>(v_ic0, g_ic0, sc_ic0, NA);
    k_rowscale<<<NL, blk, 0, stream>>>(v_mu, g_mu, sc_mu, NH);
    k_rowscale<<<NL, blk, 0, stream>>>(v_s2, g_s2, sc_s2, NH);

    // h0 = feat @ Wn_ih0.T + b_ih0 ; c0 = feat @ Wn_ic0.T + b_ic0
    k_gemm_nt<<<dim3(NH / BN, NB / BM), blk, 0, stream>>>(feat, NA, v_ih0, NA, h, NH, NA, sc_ih0, b_ih0);
    k_gemm_nt<<<dim3(NH / BN, NB / BM), blk, 0, stream>>>(feat, NA, v_ic0, NA, c, NH, NA, sc_ic0, b_ic0);

    // recurrence
    for (int t = 0; t < NT; ++t) {
        k_lstm_gates<<<dim3(4 * NH / BN, NB / BM), blk, 0, stream>>>(
            cap, embed, h, W_ih, W_hh, b_ih, b_hh, gates, t);
        k_lstm_update<<<dim3(NB * NH / 256), blk, 0, stream>>>(
            gates, h, c, cap_len, h_last, t);
    }

    // heads: mu, sigma2
    k_gemm_nt<<<dim3(NL / BN, NB / BM), blk, 0, stream>>>(h_last, NH, v_mu, NH, out, NL, NH, sc_mu, b_mu);
    k_gemm_nt<<<dim3(NL / BN, NB / BM), blk, 0, stream>>>(h_last, NH, v_s2, NH, out + (size_t)NB * NL, NL, NH, sc_s2, b_s2);
}

// Round 3
// 2444.913 us; speedup vs baseline: 3.3156x; 3.3156x over previous
//
#include <hip/hip_runtime.h>
#include <hip/hip_bf16.h>
#include <math.h>

// Problem dims
static constexpr int NB = 1024;  // batch
static constexpr int NT = 40;    // seq len
static constexpr int NE = 512;   // embed dim
static constexpr int NH = 1024;  // hidden
static constexpr int NL = 256;   // latent out
static constexpr int NA = 2048;  // feature dim
static constexpr int NK = NE + NH;   // 1536 = gates GEMM K
static constexpr int NG = 4 * NH;    // 4096 = gates GEMM N (interleaved n' = j*4+g)

// fp32 GEMM tile (init + heads)
static constexpr int BM = 64, BN = 64, BKT = 16;

typedef short bf16x8 __attribute__((ext_vector_type(8)));
typedef float f32x4 __attribute__((ext_vector_type(4)));

__device__ __forceinline__ void gload16(const void* g, void* l) {
    __builtin_amdgcn_global_load_lds(
        (const __attribute__((address_space(1))) void*)g,
        (__attribute__((address_space(3))) void*)l, 16, 0, 0);
}

__device__ __forceinline__ unsigned int pack_bf16(float a, float b) {
    __hip_bfloat16 ha = __float2bfloat16(a);
    __hip_bfloat16 hb = __float2bfloat16(b);
    unsigned short ua = *reinterpret_cast<unsigned short*>(&ha);
    unsigned short ub = *reinterpret_cast<unsigned short*>(&hb);
    return (unsigned int)ua | ((unsigned int)ub << 16);
}

__device__ __forceinline__ float sigm(float x) { return 1.f / (1.f + __expf(-x)); }

// ---------------------------------------------------------------------------
// scale[r] = g[r] / ||v[r,:]||
__global__ __launch_bounds__(256) void k_rowscale(const float* __restrict__ v,
                                                  const float* __restrict__ g,
                                                  float* __restrict__ scale,
                                                  int cols) {
    int r = blockIdx.x;
    const float* vr = v + (size_t)r * cols;
    float s = 0.f;
    for (int k = threadIdx.x; k < cols; k += 256) {
        float x = vr[k];
        s += x * x;
    }
    __shared__ float red[256];
    red[threadIdx.x] = s;
    __syncthreads();
    for (int o = 128; o > 0; o >>= 1) {
        if (threadIdx.x < o) red[threadIdx.x] += red[threadIdx.x + o];
        __syncthreads();
    }
    if (threadIdx.x == 0) scale[r] = g[r] * rsqrtf(red[0]);
}

// ---------------------------------------------------------------------------
// Wcat interleaved: row n' = j*4+g  <-  source row n = g*NH+j of [W_ih | W_hh]
__global__ __launch_bounds__(256) void k_build_wcat(const float* __restrict__ Wih,
                                                    const float* __restrict__ Whh,
                                                    unsigned short* __restrict__ Wcat) {
    int i = blockIdx.x * 256 + threadIdx.x;      // chunks of 8 elems
    if (i >= NG * NK / 8) return;
    int rp = i / (NK / 8);                       // interleaved row n'
    int p = (i % (NK / 8)) * 8;
    int n = (rp & 3) * NH + (rp >> 2);           // source row
    const float* src = (p < NE) ? (Wih + (size_t)n * NE + p)
                                : (Whh + (size_t)n * NH + (p - NE));
    const float4* q = reinterpret_cast<const float4*>(src);
    float4 x = q[0], y = q[1];
    uint4 o;
    o.x = pack_bf16(x.x, x.y);
    o.y = pack_bf16(x.z, x.w);
    o.z = pack_bf16(y.x, y.y);
    o.w = pack_bf16(y.z, y.w);
    reinterpret_cast<uint4*>(Wcat)[i] = o;
}

// ---------------------------------------------------------------------------
// x0 gather: x_b0[m][e] = bf16(embed[cap[m][0]][e])
__global__ __launch_bounds__(256) void k_gather_x0(const int* __restrict__ cap,
                                                   const float* __restrict__ embed,
                                                   unsigned short* __restrict__ x0) {
    int i = blockIdx.x * 256 + threadIdx.x;      // NB*NE/8 chunks
    if (i >= NB * NE / 8) return;
    int m = i / (NE / 8);
    int p = (i % (NE / 8)) * 8;
    int tok = cap[(size_t)m * NT];
    const float4* q = reinterpret_cast<const float4*>(embed + (size_t)tok * NE + p);
    float4 x = q[0], y = q[1];
    uint4 o;
    o.x = pack_bf16(x.x, x.y);
    o.y = pack_bf16(x.z, x.w);
    o.z = pack_bf16(y.x, y.y);
    o.w = pack_bf16(y.z, y.w);
    reinterpret_cast<uint4*>(x0)[i] = o;
}

// ---------------------------------------------------------------------------
// fp32 NT GEMM: C = (A B^T)*scale + bias ; optional bf16 output (Cb != null)
__global__ __launch_bounds__(256) void k_gemm_nt(
    const float* __restrict__ A, int lda,
    const float* __restrict__ Bm, int ldb,
    float* __restrict__ C, unsigned short* __restrict__ Cb, int ldc, int K,
    const float* __restrict__ scale,
    const float* __restrict__ bias) {
    __shared__ float As[BKT][BM + 4];
    __shared__ float Bs[BKT][BN + 4];
    const int tid = threadIdx.x;
    const int row = tid >> 2;
    const int k0 = (tid & 3) << 2;
    const int ty = tid >> 4, tx = tid & 15;
    const float* Ap = A + (size_t)(blockIdx.y * BM + row) * lda + k0;
    const float* Bp = Bm + (size_t)(blockIdx.x * BN + row) * ldb + k0;
    float acc[4][4] = {};
    for (int kt = 0; kt < K; kt += BKT) {
        float4 av = *reinterpret_cast<const float4*>(Ap + kt);
        float4 bv = *reinterpret_cast<const float4*>(Bp + kt);
        As[k0 + 0][row] = av.x; As[k0 + 1][row] = av.y;
        As[k0 + 2][row] = av.z; As[k0 + 3][row] = av.w;
        Bs[k0 + 0][row] = bv.x; Bs[k0 + 1][row] = bv.y;
        Bs[k0 + 2][row] = bv.z; Bs[k0 + 3][row] = bv.w;
        __syncthreads();
#pragma unroll
        for (int k = 0; k < BKT; ++k) {
            float a[4], b[4];
            *reinterpret_cast<float4*>(a) = *reinterpret_cast<const float4*>(&As[k][ty << 2]);
            *reinterpret_cast<float4*>(b) = *reinterpret_cast<const float4*>(&Bs[k][tx << 2]);
#pragma unroll
            for (int i = 0; i < 4; ++i)
#pragma unroll
                for (int j = 0; j < 4; ++j)
                    acc[i][j] = fmaf(a[i], b[j], acc[i][j]);
        }
        __syncthreads();
    }
    const int gm0 = blockIdx.y * BM + (ty << 2);
    const int gn0 = blockIdx.x * BN + (tx << 2);
#pragma unroll
    for (int i = 0; i < 4; ++i) {
#pragma unroll
        for (int j = 0; j < 4; ++j) {
            int gn = gn0 + j;
            float x = acc[i][j];
            if (scale) x *= scale[gn];
            if (bias) x += bias[gn];
            if (Cb) {
                __hip_bfloat16 hb = __float2bfloat16(x);
                Cb[(size_t)(gm0 + i) * ldc + gn] = *reinterpret_cast<unsigned short*>(&hb);
            } else {
                C[(size_t)(gm0 + i) * ldc + gn] = x;
            }
        }
    }
}

// ---------------------------------------------------------------------------
// Fused gates GEMM + LSTM cell update (+ x prefetch for t+1).
// GEMM: S[m,n'] = sum_k Aact[m,k]*Wcat[n',k], Aact = [x_cur | h_cur] bf16.
// Wcat rows interleaved n' = j*4+g, so tile bn owns j in [bn*32, bn*32+32)
// complete with all 4 gates -> cell update done in-block via LDS recombine.
// 128x128 tile, BK=32, 4 waves, 4x4 frags of mfma 16x16x32.
__global__ __launch_bounds__(256) void k_lstm_fused(
    const unsigned short* __restrict__ x_cur,   // [NB][NE]
    const unsigned short* __restrict__ h_cur,   // [NB][NH]
    unsigned short* __restrict__ h_nxt,         // [NB][NH]
    unsigned short* __restrict__ x_nxt,         // [NB][NE]
    const unsigned short* __restrict__ Wcat,    // [NG][NK]
    const float* __restrict__ bih,
    const float* __restrict__ bhh,
    float* __restrict__ c,                      // [NB][NH] fp32
    float* __restrict__ h_last,                 // [NB][NH] fp32
    const int* __restrict__ cap,
    const int* __restrict__ cap_len,
    const float* __restrict__ embed,
    int t, int do_gather) {
    __shared__ short As[128 * 32];
    __shared__ short Bs[128 * 32];
    __shared__ float Ls[4 * 2113];   // 4 gate planes, stride 2113 (=64*33+1)

    const int tid = threadIdx.x;
    const int wid = tid >> 6;
    const int lane = tid & 63;
    const int bn = blockIdx.x;   // 0..31
    const int bm = blockIdx.y;   // 0..7

    // ---- x prefetch for t+1 (issue loads early, write at end) ----
    float4 xg0, xg1;
    int gxm = 0, gxe = 0;
    if (do_gather) {
        gxm = bm * 128 + (tid >> 1);
        gxe = bn * 16 + (tid & 1) * 8;
        int tok = cap[(size_t)gxm * NT + t + 1];
        const float* ep = embed + (size_t)tok * NE + gxe;
        xg0 = *reinterpret_cast<const float4*>(ep);
        xg1 = *reinterpret_cast<const float4*>(ep + 4);
    }

    // ---- staging mapping ----
    const int sr = tid >> 2;           // row in half-tile, 0..63
    const int sc = (tid & 3) << 3;     // elem offset: 0,8,16,24
    const int am0 = bm * 128 + sr;
    const int am1 = am0 + 64;
    short* As0 = As + wid * 512;
    short* As1 = As + 2048 + wid * 512;
    short* Bs0 = Bs + wid * 512;
    short* Bs1 = Bs + 2048 + wid * 512;

    const int wm = wid >> 1, wn = wid & 1;
    const int lrow = lane & 15;
    const int hi4 = lane >> 4;
    const int lk = hi4 << 3;

    f32x4 zero = {0.f, 0.f, 0.f, 0.f};
    f32x4 acc[4][4];
#pragma unroll
    for (int i = 0; i < 4; ++i)
#pragma unroll
        for (int j = 0; j < 4; ++j) acc[i][j] = zero;

    const unsigned short* wrow0 = Wcat + (size_t)(bn * 128 + sr) * NK + sc;
    const unsigned short* wrow1 = wrow0 + (size_t)64 * NK;

    for (int ks = 0; ks < NK / 32; ++ks) {
        const int k0 = ks << 5;
        __syncthreads();   // previous tile consumed
        const unsigned short *ga0, *ga1;
        if (k0 < NE) {
            ga0 = x_cur + (size_t)am0 * NE + k0 + sc;
            ga1 = x_cur + (size_t)am1 * NE + k0 + sc;
        } else {
            ga0 = h_cur + (size_t)am0 * NH + (k0 - NE) + sc;
            ga1 = h_cur + (size_t)am1 * NH + (k0 - NE) + sc;
        }
        gload16(ga0, As0);
        gload16(ga1, As1);
        gload16(wrow0 + k0, Bs0);
        gload16(wrow1 + k0, Bs1);
        __syncthreads();   // vmcnt drained -> tile ready
        bf16x8 a[4], b[4];
#pragma unroll
        for (int mi = 0; mi < 4; ++mi)
            a[mi] = *reinterpret_cast<const bf16x8*>(As + (wm * 64 + mi * 16 + lrow) * 32 + lk);
#pragma unroll
        for (int ni = 0; ni < 4; ++ni)
            b[ni] = *reinterpret_cast<const bf16x8*>(Bs + (wn * 64 + ni * 16 + lrow) * 32 + lk);
#pragma unroll
        for (int mi = 0; mi < 4; ++mi)
#pragma unroll
            for (int ni = 0; ni < 4; ++ni)
                acc[mi][ni] = __builtin_amdgcn_mfma_f32_16x16x32_bf16(a[mi], b[ni], acc[mi][ni], 0, 0, 0);
    }

    // ---- epilogue: recombine gates via LDS, two m-half passes ----
    const int jl = tid & 31;           // local j
    const int jg = bn * 32 + jl;       // global j
    float bsum[4];
#pragma unroll
    for (int g = 0; g < 4; ++g) bsum[g] = bih[g * NH + jg] + bhh[g * NH + jg];
    const int mgrp = tid >> 5;         // 0..7

#pragma unroll
    for (int pass = 0; pass < 2; ++pass) {
        __syncthreads();
        if (wm == pass) {
            // C/D frag: col n'loc = wn*64+ni*16+(lane&15); row mloc = wm*64+mi*16+hi4*4+r
#pragma unroll
            for (int ni = 0; ni < 4; ++ni) {
                const int nloc = wn * 64 + ni * 16 + lrow;
                const int g = nloc & 3;
                const int jj = nloc >> 2;          // 0..31
                float* P = Ls + g * 2113 + jj;
#pragma unroll
                for (int mi = 0; mi < 4; ++mi) {
                    const int mb = mi * 16 + hi4 * 4;   // 0..63 within half
                    f32x4 v = acc[mi][ni];
#pragma unroll
                    for (int r = 0; r < 4; ++r) P[(mb + r) * 33] = v[r];
                }
            }
        }
        __syncthreads();
        // update 64 rows of this half: each thread does 8 rows at its j
#pragma unroll
        for (int mm = 0; mm < 8; ++mm) {
            const int ml = mgrp * 8 + mm;               // 0..63
            const int mg = bm * 128 + pass * 64 + ml;   // global row
            float gi = Ls[0 * 2113 + ml * 33 + jl] + bsum[0];
            float gf = Ls[1 * 2113 + ml * 33 + jl] + bsum[1];
            float gG = Ls[2 * 2113 + ml * 33 + jl] + bsum[2];
            float go = Ls[3 * 2113 + ml * 33 + jl] + bsum[3];
            const size_t ix = (size_t)mg * NH + jg;
            float cn = sigm(gf) * c[ix] + sigm(gi) * tanhf(gG);
            float hn = sigm(go) * tanhf(cn);
            c[ix] = cn;
            __hip_bfloat16 hb = __float2bfloat16(hn);
            h_nxt[ix] = *reinterpret_cast<unsigned short*>(&hb);
            if (cap_len[mg] == t + 1) h_last[ix] = hn;
        }
    }

    // ---- commit x prefetch ----
    if (do_gather) {
        uint4 o;
        o.x = pack_bf16(xg0.x, xg0.y);
        o.y = pack_bf16(xg0.z, xg0.w);
        o.z = pack_bf16(xg1.x, xg1.y);
        o.w = pack_bf16(xg1.z, xg1.w);
        *reinterpret_cast<uint4*>(x_nxt + (size_t)gxm * NE + gxe) = o;
    }
}

// ---------------------------------------------------------------------------
extern "C" void kernel_launch(void* const* d_in, const int* in_sizes, int n_in,
                              void* d_out, int out_size, void* d_ws, size_t ws_size,
                              hipStream_t stream) {
    const int* cap      = (const int*)d_in[0];
    const int* cap_len  = (const int*)d_in[1];
    const float* feat   = (const float*)d_in[2];
    const float* embed  = (const float*)d_in[3];
    const float* W_ih   = (const float*)d_in[4];
    const float* W_hh   = (const float*)d_in[5];
    const float* b_ih   = (const float*)d_in[6];
    const float* b_hh   = (const float*)d_in[7];
    const float* v_ih0  = (const float*)d_in[8];
    const float* g_ih0  = (const float*)d_in[9];
    const float* b_ih0  = (const float*)d_in[10];
    const float* v_ic0  = (const float*)d_in[11];
    const float* g_ic0  = (const float*)d_in[12];
    const float* b_ic0  = (const float*)d_in[13];
    const float* v_mu   = (const float*)d_in[14];
    const float* g_mu   = (const float*)d_in[15];
    const float* b_mu   = (const float*)d_in[16];
    const float* v_s2   = (const float*)d_in[17];
    const float* g_s2   = (const float*)d_in[18];
    const float* b_s2   = (const float*)d_in[19];
    float* out = (float*)d_out;

    // workspace layout (~26 MB)
    float* ws = (float*)d_ws;
    float* c       = ws;                                 // NB*NH        (4 MB)
    float* h_last  = c + (size_t)NB * NH;                // NB*NH        (4 MB)
    float* sc_ih0  = h_last + (size_t)NB * NH;           // NH
    float* sc_ic0  = sc_ih0 + NH;                        // NH
    float* sc_mu   = sc_ic0 + NH;                        // NL
    float* sc_s2   = sc_mu + NL;                         // NL
    float* fend    = sc_s2 + NL + 64;                    // pad (16B-aligned)
    unsigned short* Wcat = (unsigned short*)fend;        // NG*NK        (12 MB)
    unsigned short* h_b0 = Wcat + (size_t)NG * NK;       // NB*NH        (2 MB)
    unsigned short* h_b1 = h_b0 + (size_t)NB * NH;       // NB*NH        (2 MB)
    unsigned short* x_b0 = h_b1 + (size_t)NB * NH;       // NB*NE        (1 MB)
    unsigned short* x_b1 = x_b0 + (size_t)NB * NE;       // NB*NE        (1 MB)

    dim3 blk(256);

    // weight-norm row scales
    k_rowscale<<<NH, blk, 0, stream>>>(v_ih0, g_ih0, sc_ih0, NA);
    k_rowscale<<<NH, blk, 0, stream>>>(v_ic0, g_ic0, sc_ic0, NA);
    k_rowscale<<<NL, blk, 0, stream>>>(v_mu, g_mu, sc_mu, NH);
    k_rowscale<<<NL, blk, 0, stream>>>(v_s2, g_s2, sc_s2, NH);

    // interleaved bf16 weight build + x0 gather
    k_build_wcat<<<(NG * NK / 8 + 255) / 256, blk, 0, stream>>>(W_ih, W_hh, Wcat);
    k_gather_x0<<<(NB * NE / 8 + 255) / 256, blk, 0, stream>>>(cap, embed, x_b0);

    // c0 (fp32) and h0 (direct bf16)
    k_gemm_nt<<<dim3(NH / BN, NB / BM), blk, 0, stream>>>(feat, NA, v_ic0, NA, c, nullptr, NH, NA, sc_ic0, b_ic0);
    k_gemm_nt<<<dim3(NH / BN, NB / BM), blk, 0, stream>>>(feat, NA, v_ih0, NA, nullptr, h_b0, NH, NA, sc_ih0, b_ih0);

    // recurrence: fused gates GEMM + cell update + x prefetch
    unsigned short* hbuf[2] = {h_b0, h_b1};
    unsigned short* xbuf[2] = {x_b0, x_b1};
    for (int t = 0; t < NT; ++t) {
        k_lstm_fused<<<dim3(NG / 128, NB / 128), blk, 0, stream>>>(
            xbuf[t & 1], hbuf[t & 1], hbuf[(t + 1) & 1], xbuf[(t + 1) & 1],
            Wcat, b_ih, b_hh, c, h_last, cap, cap_len, embed,
            t, (t + 1 < NT) ? 1 : 0);
    }

    // heads: mu, sigma2 (fp32)
    k_gemm_nt<<<dim3(NL / BN, NB / BM), blk, 0, stream>>>(h_last, NH, v_mu, NH, out, nullptr, NL, NH, sc_mu, b_mu);
    k_gemm_nt<<<dim3(NL / BN, NB / BM), blk, 0, stream>>>(h_last, NH, v_s2, NH, out + (size_t)NB * NL, nullptr, NL, NH, sc_s2, b_s2);
}

// Round 9
// 1549.523 us; speedup vs baseline: 5.2315x; 1.5778x over previous
//
#include <hip/hip_runtime.h>
#include <hip/hip_bf16.h>
#include <math.h>

// Problem dims
static constexpr int NB = 1024;  // batch
static constexpr int NT = 40;    // seq len
static constexpr int NE = 512;   // embed dim
static constexpr int NH = 1024;  // hidden
static constexpr int NL = 256;   // latent out
static constexpr int NA = 2048;  // feature dim
static constexpr int NK = NE + NH;   // 1536 gates GEMM K
static constexpr int NG = 4 * NH;    // 4096 gates GEMM N (interleaved n' = j*4+g)

typedef short bf16x8 __attribute__((ext_vector_type(8)));
typedef float f32x4 __attribute__((ext_vector_type(4)));

__device__ __forceinline__ void gload16(const void* g, void* l) {
    __builtin_amdgcn_global_load_lds(
        (const __attribute__((address_space(1))) void*)g,
        (__attribute__((address_space(3))) void*)l, 16, 0, 0);
}

__device__ __forceinline__ unsigned int pack_bf16(float a, float b) {
    __hip_bfloat16 ha = __float2bfloat16(a);
    __hip_bfloat16 hb = __float2bfloat16(b);
    unsigned short ua = *reinterpret_cast<unsigned short*>(&ha);
    unsigned short ub = *reinterpret_cast<unsigned short*>(&hb);
    return (unsigned int)ua | ((unsigned int)ub << 16);
}

__device__ __forceinline__ float sigm(float x) { return 1.f / (1.f + __expf(-x)); }

// vmcnt(0)-drain + raw barrier + scheduler pin (T3-min recipe)
__device__ __forceinline__ void vmbar() {
    asm volatile("s_waitcnt vmcnt(0)" ::: "memory");
    __builtin_amdgcn_s_barrier();
    __builtin_amdgcn_sched_barrier(0);
}

// ---------------------------------------------------------------------------
__global__ __launch_bounds__(256) void k_rowscale(const float* __restrict__ v,
                                                  const float* __restrict__ g,
                                                  float* __restrict__ scale,
                                                  int cols) {
    int r = blockIdx.x;
    const float* vr = v + (size_t)r * cols;
    float s = 0.f;
    for (int k = threadIdx.x; k < cols; k += 256) {
        float x = vr[k];
        s += x * x;
    }
    __shared__ float red[256];
    red[threadIdx.x] = s;
    __syncthreads();
    for (int o = 128; o > 0; o >>= 1) {
        if (threadIdx.x < o) red[threadIdx.x] += red[threadIdx.x + o];
        __syncthreads();
    }
    if (threadIdx.x == 0) scale[r] = g[r] * rsqrtf(red[0]);
}

// ---------------------------------------------------------------------------
// Wcat interleaved: row n' = j*4+g  <-  source row n = g*NH+j of [W_ih | W_hh]
__global__ __launch_bounds__(256) void k_build_wcat(const float* __restrict__ Wih,
                                                    const float* __restrict__ Whh,
                                                    unsigned short* __restrict__ Wcat) {
    int i = blockIdx.x * 256 + threadIdx.x;
    if (i >= NG * NK / 8) return;
    int rp = i / (NK / 8);
    int p = (i % (NK / 8)) * 8;
    int n = (rp & 3) * NH + (rp >> 2);
    const float* src = (p < NE) ? (Wih + (size_t)n * NE + p)
                                : (Whh + (size_t)n * NH + (p - NE));
    const float4* q = reinterpret_cast<const float4*>(src);
    float4 x = q[0], y = q[1];
    uint4 o;
    o.x = pack_bf16(x.x, x.y);
    o.y = pack_bf16(x.z, x.w);
    o.z = pack_bf16(y.x, y.y);
    o.w = pack_bf16(y.z, y.w);
    reinterpret_cast<uint4*>(Wcat)[i] = o;
}

// ---------------------------------------------------------------------------
__global__ __launch_bounds__(256) void k_gather_x0(const int* __restrict__ cap,
                                                   const float* __restrict__ embed,
                                                   unsigned short* __restrict__ x0) {
    int i = blockIdx.x * 256 + threadIdx.x;
    if (i >= NB * NE / 8) return;
    int m = i / (NE / 8);
    int p = (i % (NE / 8)) * 8;
    int tok = cap[(size_t)m * NT];
    const float4* q = reinterpret_cast<const float4*>(embed + (size_t)tok * NE + p);
    float4 x = q[0], y = q[1];
    uint4 o;
    o.x = pack_bf16(x.x, x.y);
    o.y = pack_bf16(x.z, x.w);
    o.z = pack_bf16(y.x, y.y);
    o.w = pack_bf16(y.z, y.w);
    reinterpret_cast<uint4*>(x0)[i] = o;
}

// ---------------------------------------------------------------------------
// bf16-MFMA GEMM for weight-normed layers, fp32 inputs reg-staged + converted.
// C[m,n] = (sum_k A[m,k]*Bv[n,k]*sc[n]) + bias[n]. Two stacked weight sets
// selected by bn (init: h0|c0, heads: mu|sigma2). 128x128 tile, BK=64.
__global__ __launch_bounds__(256) void k_gemm_wn(
    const float* __restrict__ A, int lda, int K,
    const float* __restrict__ B1, const float* __restrict__ s1, const float* __restrict__ b1,
    float* __restrict__ Cf1, unsigned short* __restrict__ Cb1, int ldc1,
    const float* __restrict__ B2, const float* __restrict__ s2, const float* __restrict__ b2,
    float* __restrict__ Cf2, unsigned short* __restrict__ Cb2, int ldc2,
    int ntile1) {
    __shared__ short As[8192];   // [128][64] bf16, XOR-swizzled
    __shared__ short Bs[8192];
    const int tid = threadIdx.x, wid = tid >> 6, lane = tid & 63;
    int bn = blockIdx.x;
    const int bm = blockIdx.y;
    const float *Bv, *sc, *bias;
    float* Cf; unsigned short* Cb; int ldc;
    if (bn < ntile1) { Bv = B1; sc = s1; bias = b1; Cf = Cf1; Cb = Cb1; ldc = ldc1; }
    else { bn -= ntile1; Bv = B2; sc = s2; bias = b2; Cf = Cf2; Cb = Cb2; ldc = ldc2; }
    const int wm = wid >> 1, wn = wid & 1, lrow = lane & 15, q = lane >> 4;
    const int xorv = (lrow & 7) << 4;
    const int sr = tid >> 1;           // staged row 0..127
    const int sc32 = (tid & 1) * 32;   // staged col offset (elems)
    const int wxor = (sr & 7) << 4;
    const float* Arow = A + (size_t)(bm * 128 + sr) * lda + sc32;
    const float* Brow = Bv + (size_t)(bn * 128 + sr) * K + sc32;
    const float brs = sc[bn * 128 + sr];

    f32x4 acc[4][4];
#pragma unroll
    for (int i = 0; i < 4; ++i)
#pragma unroll
        for (int j = 0; j < 4; ++j) acc[i][j] = {0.f, 0.f, 0.f, 0.f};

    char* ad = (char*)As;
    char* bd = (char*)Bs;
    const int rbase = sr * 128 + sc32 * 2;

    for (int kt = 0; kt < K; kt += 64) {
        float4 av[8], bv[8];
#pragma unroll
        for (int u = 0; u < 8; ++u) {
            av[u] = *reinterpret_cast<const float4*>(Arow + kt + u * 4);
            bv[u] = *reinterpret_cast<const float4*>(Brow + kt + u * 4);
        }
        __syncthreads();
#pragma unroll
        for (int u = 0; u < 4; ++u) {
            uint4 wa, wb;
            wa.x = pack_bf16(av[2*u].x, av[2*u].y);
            wa.y = pack_bf16(av[2*u].z, av[2*u].w);
            wa.z = pack_bf16(av[2*u+1].x, av[2*u+1].y);
            wa.w = pack_bf16(av[2*u+1].z, av[2*u+1].w);
            wb.x = pack_bf16(bv[2*u].x * brs, bv[2*u].y * brs);
            wb.y = pack_bf16(bv[2*u].z * brs, bv[2*u].w * brs);
            wb.z = pack_bf16(bv[2*u+1].x * brs, bv[2*u+1].y * brs);
            wb.w = pack_bf16(bv[2*u+1].z * brs, bv[2*u+1].w * brs);
            *reinterpret_cast<uint4*>(ad + ((rbase + u * 16) ^ wxor)) = wa;
            *reinterpret_cast<uint4*>(bd + ((rbase + u * 16) ^ wxor)) = wb;
        }
        __syncthreads();
#pragma unroll
        for (int kk = 0; kk < 2; ++kk) {
            bf16x8 a[4], b[4];
#pragma unroll
            for (int mi = 0; mi < 4; ++mi)
                a[mi] = *reinterpret_cast<const bf16x8*>(
                    ad + ((((wm*64 + mi*16 + lrow) << 7) + (kk << 6) + (q << 4)) ^ xorv));
#pragma unroll
            for (int ni = 0; ni < 4; ++ni)
                b[ni] = *reinterpret_cast<const bf16x8*>(
                    bd + ((((wn*64 + ni*16 + lrow) << 7) + (kk << 6) + (q << 4)) ^ xorv));
#pragma unroll
            for (int mi = 0; mi < 4; ++mi)
#pragma unroll
                for (int ni = 0; ni < 4; ++ni)
                    acc[mi][ni] = __builtin_amdgcn_mfma_f32_16x16x32_bf16(a[mi], b[ni], acc[mi][ni], 0, 0, 0);
        }
    }
    const int n0 = bn * 128 + wn * 64;
    const int m0 = bm * 128 + wm * 64 + q * 4;
#pragma unroll
    for (int ni = 0; ni < 4; ++ni) {
        const int n = n0 + ni * 16 + lrow;
        const float bs = bias[n];
#pragma unroll
        for (int mi = 0; mi < 4; ++mi) {
            f32x4 v = acc[mi][ni];
#pragma unroll
            for (int r = 0; r < 4; ++r) {
                const int m = m0 + mi * 16 + r;
                float x = v[r] + bs;
                if (Cb) {
                    __hip_bfloat16 hb = __float2bfloat16(x);
                    Cb[(size_t)m * ldc + n] = *reinterpret_cast<unsigned short*>(&hb);
                } else {
                    Cf[(size_t)m * ldc + n] = x;
                }
            }
        }
    }
}

// ---------------------------------------------------------------------------
// Fused gates GEMM + LSTM cell update (+ x prefetch for t+1).
// 128x128 tile, BK=64, double-buffered LDS, 2-phase pipeline (counted-vm
// drain AFTER compute), XOR-swizzled LDS, XCD-pinned bn mapping.
__global__ __launch_bounds__(256) void k_lstm_fused(
    const unsigned short* __restrict__ x_cur,   // [NB][NE]
    const unsigned short* __restrict__ h_cur,   // [NB][NH]
    unsigned short* __restrict__ h_nxt,
    unsigned short* __restrict__ x_nxt,
    const unsigned short* __restrict__ Wcat,    // [NG][NK]
    const float* __restrict__ bih,
    const float* __restrict__ bhh,
    float* __restrict__ c,                      // [NB][NH] fp32
    float* __restrict__ h_last,                 // [NB][NH] fp32
    const int* __restrict__ cap,
    const int* __restrict__ cap_len,
    const float* __restrict__ embed,
    int t, int do_gather) {
    __shared__ char smem[65536];                // 2 bufs x (A 16K | B 16K); epilogue aliases
    short* buf0 = (short*)smem;
    short* buf1 = (short*)(smem + 32768);

    const int tid = threadIdx.x;
    const int wid = tid >> 6;
    const int lane = tid & 63;
    // XCD-pinned tile mapping: blocks on XCD x use bn in [x*4, x*4+4)
    const int g = blockIdx.x;                   // 0..255
    const int xcd = g & 7;
    const int w = g >> 3;                       // 0..31
    const int bm = w >> 2;                      // 0..7
    const int bn = xcd * 4 + (w & 3);           // 0..31

    // ---- x prefetch for t+1 (issued first; committed at end) ----
    float4 xg0, xg1;
    int gxm = 0, gxe = 0;
    if (do_gather) {
        gxm = bm * 128 + (tid >> 1);
        gxe = bn * 16 + (tid & 1) * 8;
        int tok = cap[(size_t)gxm * NT + t + 1];
        const float* ep = embed + (size_t)tok * NE + gxe;
        xg0 = *reinterpret_cast<const float4*>(ep);
        xg1 = *reinterpret_cast<const float4*>(ep + 4);
    }

    // ---- staging constants ----
    // linear LDS byte L = j*4096 + tid*16; row = j*32 + (tid>>3); colB=(tid&7)*16
    // pre-swizzled source col: colB ^ ((row&7)<<4), row&7 = (tid>>3)&7
    const int srow8 = tid >> 3;                              // 0..31
    const int scole = (((tid & 7) * 16) ^ (((tid >> 3) & 7) << 4)) >> 1;  // elem offset

    const int wm = wid >> 1, wn = wid & 1;
    const int lrow = lane & 15;
    const int q = lane >> 4;
    const int xorv = (lrow & 7) << 4;

    f32x4 acc[4][4];
#pragma unroll
    for (int i = 0; i < 4; ++i)
#pragma unroll
        for (int j = 0; j < 4; ++j) acc[i][j] = {0.f, 0.f, 0.f, 0.f};

    auto STAGE = [&](short* dst, int ksn) {
        const int k0 = ksn << 6;
        char* dA = (char*)dst;
        char* dB = dA + 16384;
        const bool isx = (ksn < 8);
#pragma unroll
        for (int j = 0; j < 4; ++j) {
            const int row = j * 32 + srow8;
            const unsigned short* asrc = isx
                ? x_cur + (size_t)(bm * 128 + row) * NE + (k0 + scole)
                : h_cur + (size_t)(bm * 128 + row) * NH + (k0 - NE + scole);
            gload16(asrc, dA + j * 4096 + wid * 1024);
            const unsigned short* bsrc = Wcat + (size_t)(bn * 128 + row) * NK + k0 + scole;
            gload16(bsrc, dB + j * 4096 + wid * 1024);
        }
    };

    auto COMPUTE = [&](const short* src) {
        const char* ac = (const char*)src;
        const char* bc = ac + 16384;
#pragma unroll
        for (int kk = 0; kk < 2; ++kk) {
            bf16x8 a[4], b[4];
#pragma unroll
            for (int mi = 0; mi < 4; ++mi)
                a[mi] = *reinterpret_cast<const bf16x8*>(
                    ac + ((((wm*64 + mi*16 + lrow) << 7) + (kk << 6) + (q << 4)) ^ xorv));
#pragma unroll
            for (int ni = 0; ni < 4; ++ni)
                b[ni] = *reinterpret_cast<const bf16x8*>(
                    bc + ((((wn*64 + ni*16 + lrow) << 7) + (kk << 6) + (q << 4)) ^ xorv));
#pragma unroll
            for (int mi = 0; mi < 4; ++mi)
#pragma unroll
                for (int ni = 0; ni < 4; ++ni)
                    acc[mi][ni] = __builtin_amdgcn_mfma_f32_16x16x32_bf16(a[mi], b[ni], acc[mi][ni], 0, 0, 0);
        }
    };

    // ---- pipelined K-loop (24 steps) ----
    STAGE(buf0, 0);
    vmbar();
    int cur = 0;
    for (int ks = 0; ks < 24; ++ks) {
        short* curb = cur ? buf1 : buf0;
        short* nxtb = cur ? buf0 : buf1;
        if (ks < 23) STAGE(nxtb, ks + 1);   // latency hides under COMPUTE
        COMPUTE(curb);
        vmbar();                            // next buffer ready; cur fully read
        cur ^= 1;
    }

    // ---- epilogue: recombine gates via LDS (aliases smem), cell update ----
    __syncthreads();
    float* Ls = (float*)smem;               // 4 planes x 2113 floats
    const int jl = tid & 31;
    const int jg = bn * 32 + jl;
    float bsum[4];
#pragma unroll
    for (int gg = 0; gg < 4; ++gg) bsum[gg] = bih[gg * NH + jg] + bhh[gg * NH + jg];
    const int mgrp = tid >> 5;

#pragma unroll
    for (int pass = 0; pass < 2; ++pass) {
        __syncthreads();
        if (wm == pass) {
#pragma unroll
            for (int ni = 0; ni < 4; ++ni) {
                const int nloc = wn * 64 + ni * 16 + lrow;
                const int gg = nloc & 3;
                const int jj = nloc >> 2;
                float* P = Ls + gg * 2113 + jj;
#pragma unroll
                for (int mi = 0; mi < 4; ++mi) {
                    const int mb = mi * 16 + q * 4;
                    f32x4 v = acc[mi][ni];
#pragma unroll
                    for (int r = 0; r < 4; ++r) P[(mb + r) * 33] = v[r];
                }
            }
        }
        __syncthreads();
#pragma unroll
        for (int mm = 0; mm < 8; ++mm) {
            const int ml = mgrp * 8 + mm;
            const int mg = bm * 128 + pass * 64 + ml;
            float gi = Ls[0 * 2113 + ml * 33 + jl] + bsum[0];
            float gf = Ls[1 * 2113 + ml * 33 + jl] + bsum[1];
            float gG = Ls[2 * 2113 + ml * 33 + jl] + bsum[2];
            float go = Ls[3 * 2113 + ml * 33 + jl] + bsum[3];
            const size_t ix = (size_t)mg * NH + jg;
            float cn = sigm(gf) * c[ix] + sigm(gi) * tanhf(gG);
            float hn = sigm(go) * tanhf(cn);
            c[ix] = cn;
            __hip_bfloat16 hb = __float2bfloat16(hn);
            h_nxt[ix] = *reinterpret_cast<unsigned short*>(&hb);
            if (cap_len[mg] == t + 1) h_last[ix] = hn;
        }
    }

    // ---- commit x prefetch ----
    if (do_gather) {
        uint4 o;
        o.x = pack_bf16(xg0.x, xg0.y);
        o.y = pack_bf16(xg0.z, xg0.w);
        o.z = pack_bf16(xg1.x, xg1.y);
        o.w = pack_bf16(xg1.z, xg1.w);
        *reinterpret_cast<uint4*>(x_nxt + (size_t)gxm * NE + gxe) = o;
    }
}

// ---------------------------------------------------------------------------
extern "C" void kernel_launch(void* const* d_in, const int* in_sizes, int n_in,
                              void* d_out, int out_size, void* d_ws, size_t ws_size,
                              hipStream_t stream) {
    const int* cap      = (const int*)d_in[0];
    const int* cap_len  = (const int*)d_in[1];
    const float* feat   = (const float*)d_in[2];
    const float* embed  = (const float*)d_in[3];
    const float* W_ih   = (const float*)d_in[4];
    const float* W_hh   = (const float*)d_in[5];
    const float* b_ih   = (const float*)d_in[6];
    const float* b_hh   = (const float*)d_in[7];
    const float* v_ih0  = (const float*)d_in[8];
    const float* g_ih0  = (const float*)d_in[9];
    const float* b_ih0  = (const float*)d_in[10];
    const float* v_ic0  = (const float*)d_in[11];
    const float* g_ic0  = (const float*)d_in[12];
    const float* b_ic0  = (const float*)d_in[13];
    const float* v_mu   = (const float*)d_in[14];
    const float* g_mu   = (const float*)d_in[15];
    const float* b_mu   = (const float*)d_in[16];
    const float* v_s2   = (const float*)d_in[17];
    const float* g_s2   = (const float*)d_in[18];
    const float* b_s2   = (const float*)d_in[19];
    float* out = (float*)d_out;

    // workspace (~26.6 MB)
    float* ws = (float*)d_ws;
    float* c       = ws;                                 // NB*NH
    float* h_last  = c + (size_t)NB * NH;                // NB*NH
    float* sc_ih0  = h_last + (size_t)NB * NH;           // NH
    float* sc_ic0  = sc_ih0 + NH;                        // NH
    float* sc_mu   = sc_ic0 + NH;                        // NL
    float* sc_s2   = sc_mu + NL;                         // NL
    float* fend    = sc_s2 + NL + 64;
    unsigned short* Wcat = (unsigned short*)fend;        // NG*NK
    unsigned short* h_b0 = Wcat + (size_t)NG * NK;       // NB*NH
    unsigned short* h_b1 = h_b0 + (size_t)NB * NH;       // NB*NH
    unsigned short* x_b0 = h_b1 + (size_t)NB * NH;       // NB*NE
    unsigned short* x_b1 = x_b0 + (size_t)NB * NE;       // NB*NE

    dim3 blk(256);

    k_rowscale<<<NH, blk, 0, stream>>>(v_ih0, g_ih0, sc_ih0, NA);
    k_rowscale<<<NH, blk, 0, stream>>>(v_ic0, g_ic0, sc_ic0, NA);
    k_rowscale<<<NL, blk, 0, stream>>>(v_mu, g_mu, sc_mu, NH);
    k_rowscale<<<NL, blk, 0, stream>>>(v_s2, g_s2, sc_s2, NH);

    k_build_wcat<<<(NG * NK / 8 + 255) / 256, blk, 0, stream>>>(W_ih, W_hh, Wcat);
    k_gather_x0<<<(NB * NE / 8 + 255) / 256, blk, 0, stream>>>(cap, embed, x_b0);

    // init: h0 (bf16 out) | c0 (fp32 out) in one dispatch, K=2048
    k_gemm_wn<<<dim3(16, 8), blk, 0, stream>>>(
        feat, NA, NA,
        v_ih0, sc_ih0, b_ih0, nullptr, h_b0, NH,
        v_ic0, sc_ic0, b_ic0, c, nullptr, NH, 8);

    unsigned short* hbuf[2] = {h_b0, h_b1};
    unsigned short* xbuf[2] = {x_b0, x_b1};
    for (int t = 0; t < NT; ++t) {
        k_lstm_fused<<<dim3(256), blk, 0, stream>>>(
            xbuf[t & 1], hbuf[t & 1], hbuf[(t + 1) & 1], xbuf[(t + 1) & 1],
            Wcat, b_ih, b_hh, c, h_last, cap, cap_len, embed,
            t, (t + 1 < NT) ? 1 : 0);
    }

    // heads: mu | sigma2 in one dispatch, K=1024
    k_gemm_wn<<<dim3(4, 8), blk, 0, stream>>>(
        h_last, NH, NH,
        v_mu, sc_mu, b_mu, out, nullptr, NL,
        v_s2, sc_s2, b_s2, out + (size_t)NB * NL, nullptr, NL, 2);
}

// Round 11
// 1222.291 us; speedup vs baseline: 6.6321x; 1.2677x over previous
//
#include <hip/hip_runtime.h>
#include <hip/hip_bf16.h>
#include <math.h>

// Problem dims
static constexpr int NB = 1024;  // batch
static constexpr int NT = 40;    // seq len
static constexpr int NE = 512;   // embed dim
static constexpr int NH = 1024;  // hidden
static constexpr int NL = 256;   // latent out
static constexpr int NA = 2048;  // feature dim
static constexpr int NK = NE + NH;   // 1536 gates GEMM K
static constexpr int NG = 4 * NH;    // 4096 gates GEMM N (interleaved n' = j*4+g)

typedef short bf16x8 __attribute__((ext_vector_type(8)));
typedef float f32x4 __attribute__((ext_vector_type(4)));

__device__ __forceinline__ void gload16(const void* g, void* l) {
    __builtin_amdgcn_global_load_lds(
        (const __attribute__((address_space(1))) void*)g,
        (__attribute__((address_space(3))) void*)l, 16, 0, 0);
}

__device__ __forceinline__ unsigned int pack_bf16(float a, float b) {
    __hip_bfloat16 ha = __float2bfloat16(a);
    __hip_bfloat16 hb = __float2bfloat16(b);
    unsigned short ua = *reinterpret_cast<unsigned short*>(&ha);
    unsigned short ub = *reinterpret_cast<unsigned short*>(&hb);
    return (unsigned int)ua | ((unsigned int)ub << 16);
}

__device__ __forceinline__ float sigm(float x) { return 1.f / (1.f + __expf(-x)); }

// vmcnt(0)-drain + raw barrier + scheduler pin (T3-min recipe)
__device__ __forceinline__ void vmbar() {
    asm volatile("s_waitcnt vmcnt(0)" ::: "memory");
    __builtin_amdgcn_s_barrier();
    __builtin_amdgcn_sched_barrier(0);
}

// ---------------------------------------------------------------------------
__global__ __launch_bounds__(256) void k_rowscale(const float* __restrict__ v,
                                                  const float* __restrict__ g,
                                                  float* __restrict__ scale,
                                                  int cols) {
    int r = blockIdx.x;
    const float* vr = v + (size_t)r * cols;
    float s = 0.f;
    for (int k = threadIdx.x; k < cols; k += 256) {
        float x = vr[k];
        s += x * x;
    }
    __shared__ float red[256];
    red[threadIdx.x] = s;
    __syncthreads();
    for (int o = 128; o > 0; o >>= 1) {
        if (threadIdx.x < o) red[threadIdx.x] += red[threadIdx.x + o];
        __syncthreads();
    }
    if (threadIdx.x == 0) scale[r] = g[r] * rsqrtf(red[0]);
}

// ---------------------------------------------------------------------------
// Wcat interleaved: row n' = j*4+g  <-  source row n = g*NH+j of [W_ih | W_hh]
__global__ __launch_bounds__(256) void k_build_wcat(const float* __restrict__ Wih,
                                                    const float* __restrict__ Whh,
                                                    unsigned short* __restrict__ Wcat) {
    int i = blockIdx.x * 256 + threadIdx.x;
    if (i >= NG * NK / 8) return;
    int rp = i / (NK / 8);
    int p = (i % (NK / 8)) * 8;
    int n = (rp & 3) * NH + (rp >> 2);
    const float* src = (p < NE) ? (Wih + (size_t)n * NE + p)
                                : (Whh + (size_t)n * NH + (p - NE));
    const float4* q = reinterpret_cast<const float4*>(src);
    float4 x = q[0], y = q[1];
    uint4 o;
    o.x = pack_bf16(x.x, x.y);
    o.y = pack_bf16(x.z, x.w);
    o.z = pack_bf16(y.x, y.y);
    o.w = pack_bf16(y.z, y.w);
    reinterpret_cast<uint4*>(Wcat)[i] = o;
}

// ---------------------------------------------------------------------------
__global__ __launch_bounds__(256) void k_gather_x0(const int* __restrict__ cap,
                                                   const float* __restrict__ embed,
                                                   unsigned short* __restrict__ x0) {
    int i = blockIdx.x * 256 + threadIdx.x;
    if (i >= NB * NE / 8) return;
    int m = i / (NE / 8);
    int p = (i % (NE / 8)) * 8;
    int tok = cap[(size_t)m * NT];
    const float4* q = reinterpret_cast<const float4*>(embed + (size_t)tok * NE + p);
    float4 x = q[0], y = q[1];
    uint4 o;
    o.x = pack_bf16(x.x, x.y);
    o.y = pack_bf16(x.z, x.w);
    o.z = pack_bf16(y.x, y.y);
    o.w = pack_bf16(y.z, y.w);
    reinterpret_cast<uint4*>(x0)[i] = o;
}

// ---------------------------------------------------------------------------
// bf16-MFMA GEMM for weight-normed layers, fp32 inputs reg-staged + converted.
// 64x64 tile, BK=64, 4 waves (2m x 2n, 32x32 each) -> init grid 512 (2/CU).
__global__ __launch_bounds__(256) void k_gemm_wn(
    const float* __restrict__ A, int lda, int K,
    const float* __restrict__ B1, const float* __restrict__ s1, const float* __restrict__ b1,
    float* __restrict__ Cf1, unsigned short* __restrict__ Cb1, int ldc1,
    const float* __restrict__ B2, const float* __restrict__ s2, const float* __restrict__ b2,
    float* __restrict__ Cf2, unsigned short* __restrict__ Cb2, int ldc2,
    int ntile1) {
    __shared__ short As[4096];   // [64][64] bf16, XOR-swizzled rows (128B)
    __shared__ short Bs[4096];
    const int tid = threadIdx.x, wid = tid >> 6, lane = tid & 63;
    int bn = blockIdx.x;
    const int bm = blockIdx.y;
    const float *Bv, *sc, *bias;
    float* Cf; unsigned short* Cb; int ldc;
    if (bn < ntile1) { Bv = B1; sc = s1; bias = b1; Cf = Cf1; Cb = Cb1; ldc = ldc1; }
    else { bn -= ntile1; Bv = B2; sc = s2; bias = b2; Cf = Cf2; Cb = Cb2; ldc = ldc2; }
    const int wm = wid >> 1, wn = wid & 1, lrow = lane & 15, q = lane >> 4;
    const int xorv = (lrow & 7) << 4;
    const int sr = tid >> 2;           // staged row 0..63
    const int sq = tid & 3;            // 16-elem group
    const int wxor = (sr & 7) << 4;
    const float* Arow = A + (size_t)(bm * 64 + sr) * lda + sq * 16;
    const float* Brow = Bv + (size_t)(bn * 64 + sr) * K + sq * 16;
    const float brs = sc[bn * 64 + sr];

    f32x4 acc[2][2];
#pragma unroll
    for (int i = 0; i < 2; ++i)
#pragma unroll
        for (int j = 0; j < 2; ++j) acc[i][j] = {0.f, 0.f, 0.f, 0.f};

    char* ad = (char*)As;
    char* bd = (char*)Bs;
    const int rbase = sr * 128 + sq * 32;

    for (int kt = 0; kt < K; kt += 64) {
        float4 av[4], bv[4];
#pragma unroll
        for (int u = 0; u < 4; ++u) {
            av[u] = *reinterpret_cast<const float4*>(Arow + kt + u * 4);
            bv[u] = *reinterpret_cast<const float4*>(Brow + kt + u * 4);
        }
        __syncthreads();
#pragma unroll
        for (int u = 0; u < 2; ++u) {
            uint4 wa, wb;
            wa.x = pack_bf16(av[2*u].x, av[2*u].y);
            wa.y = pack_bf16(av[2*u].z, av[2*u].w);
            wa.z = pack_bf16(av[2*u+1].x, av[2*u+1].y);
            wa.w = pack_bf16(av[2*u+1].z, av[2*u+1].w);
            wb.x = pack_bf16(bv[2*u].x * brs, bv[2*u].y * brs);
            wb.y = pack_bf16(bv[2*u].z * brs, bv[2*u].w * brs);
            wb.z = pack_bf16(bv[2*u+1].x * brs, bv[2*u+1].y * brs);
            wb.w = pack_bf16(bv[2*u+1].z * brs, bv[2*u+1].w * brs);
            *reinterpret_cast<uint4*>(ad + ((rbase + u * 16) ^ wxor)) = wa;
            *reinterpret_cast<uint4*>(bd + ((rbase + u * 16) ^ wxor)) = wb;
        }
        __syncthreads();
#pragma unroll
        for (int kk = 0; kk < 2; ++kk) {
            bf16x8 a[2], b[2];
#pragma unroll
            for (int mi = 0; mi < 2; ++mi)
                a[mi] = *reinterpret_cast<const bf16x8*>(
                    ad + ((((wm*32 + mi*16 + lrow) << 7) + (kk << 6) + (q << 4)) ^ xorv));
#pragma unroll
            for (int ni = 0; ni < 2; ++ni)
                b[ni] = *reinterpret_cast<const bf16x8*>(
                    bd + ((((wn*32 + ni*16 + lrow) << 7) + (kk << 6) + (q << 4)) ^ xorv));
#pragma unroll
            for (int mi = 0; mi < 2; ++mi)
#pragma unroll
                for (int ni = 0; ni < 2; ++ni)
                    acc[mi][ni] = __builtin_amdgcn_mfma_f32_16x16x32_bf16(a[mi], b[ni], acc[mi][ni], 0, 0, 0);
        }
    }
    const int n0 = bn * 64 + wn * 32;
    const int m0 = bm * 64 + wm * 32 + q * 4;
#pragma unroll
    for (int ni = 0; ni < 2; ++ni) {
        const int n = n0 + ni * 16 + lrow;
        const float bs = bias[n];
#pragma unroll
        for (int mi = 0; mi < 2; ++mi) {
            f32x4 v = acc[mi][ni];
#pragma unroll
            for (int r = 0; r < 4; ++r) {
                const int m = m0 + mi * 16 + r;
                float x = v[r] + bs;
                if (Cb) {
                    __hip_bfloat16 hb = __float2bfloat16(x);
                    Cb[(size_t)m * ldc + n] = *reinterpret_cast<unsigned short*>(&hb);
                } else {
                    Cf[(size_t)m * ldc + n] = x;
                }
            }
        }
    }
}

// ---------------------------------------------------------------------------
// Fused gates GEMM + LSTM cell update (+ x prefetch for t+1).
// 128x64 tile, BK=64, dbuf LDS (48KB), 2-phase pipeline, XOR swizzle,
// XCD-pinned bn. Grid 512 = 2 blocks/CU (TLP fix for R9's 1-block/CU stall).
__global__ __launch_bounds__(256) void k_lstm_fused(
    const unsigned short* __restrict__ x_cur,   // [NB][NE]
    const unsigned short* __restrict__ h_cur,   // [NB][NH]
    unsigned short* __restrict__ h_nxt,
    unsigned short* __restrict__ x_nxt,
    const unsigned short* __restrict__ Wcat,    // [NG][NK]
    const float* __restrict__ bih,
    const float* __restrict__ bhh,
    float* __restrict__ c,                      // [NB][NH] fp32
    float* __restrict__ h_last,                 // [NB][NH] fp32
    const int* __restrict__ cap,
    const int* __restrict__ cap_len,
    const float* __restrict__ embed,
    int t, int do_gather) {
    __shared__ char smem[49152];                // 2 bufs x (A 16K | B 8K); epilogue aliases
    short* buf0 = (short*)smem;
    short* buf1 = (short*)(smem + 24576);

    const int tid = threadIdx.x;
    const int wid = tid >> 6;
    const int lane = tid & 63;
    // XCD-pinned tile mapping: 512 blocks; XCD x owns bn in [x*8, x*8+8)
    const int g = blockIdx.x;                   // 0..511
    const int xcd = g & 7;
    const int w = g >> 3;                       // 0..63
    const int bm = w >> 3;                      // 0..7
    const int bn = xcd * 8 + (w & 7);           // 0..63

    // ---- x prefetch for t+1 (issued first; committed at end) ----
    // block covers rows [bm*128,+128) x cols [bn*8,+8) of x_nxt
    float4 xg;
    int gxm = 0, gxe = 0;
    if (do_gather) {
        gxm = bm * 128 + (tid >> 1);
        gxe = bn * 8 + (tid & 1) * 4;
        int tok = cap[(size_t)gxm * NT + t + 1];
        xg = *reinterpret_cast<const float4*>(embed + (size_t)tok * NE + gxe);
    }

    // ---- staging constants ----
    // linear LDS byte L = j*4096 + tid*16; row = j*32 + (tid>>3); colB=(tid&7)*16
    // pre-swizzled source col: colB ^ ((row&7)<<4)
    const int srow8 = tid >> 3;                              // 0..31
    const int scole = (((tid & 7) * 16) ^ (((tid >> 3) & 7) << 4)) >> 1;  // elem offset

    const int wm = wid >> 1, wn = wid & 1;
    const int lrow = lane & 15;
    const int q = lane >> 4;
    const int xorv = (lrow & 7) << 4;

    f32x4 acc[4][2];
#pragma unroll
    for (int i = 0; i < 4; ++i)
#pragma unroll
        for (int j = 0; j < 2; ++j) acc[i][j] = {0.f, 0.f, 0.f, 0.f};

    auto STAGE = [&](short* dst, int ksn) {
        const int k0 = ksn << 6;
        char* dA = (char*)dst;
        char* dB = dA + 16384;
        const bool isx = (ksn < 8);
#pragma unroll
        for (int j = 0; j < 4; ++j) {           // A: 128 rows
            const int row = j * 32 + srow8;
            const unsigned short* asrc = isx
                ? x_cur + (size_t)(bm * 128 + row) * NE + (k0 + scole)
                : h_cur + (size_t)(bm * 128 + row) * NH + (k0 - NE + scole);
            gload16(asrc, dA + j * 4096 + wid * 1024);
        }
#pragma unroll
        for (int j = 0; j < 2; ++j) {           // B: 64 rows
            const int row = j * 32 + srow8;
            const unsigned short* bsrc = Wcat + (size_t)(bn * 64 + row) * NK + k0 + scole;
            gload16(bsrc, dB + j * 4096 + wid * 1024);
        }
    };

    auto COMPUTE = [&](const short* src) {
        const char* ac = (const char*)src;
        const char* bc = ac + 16384;
#pragma unroll
        for (int kk = 0; kk < 2; ++kk) {
            bf16x8 a[4], b[2];
#pragma unroll
            for (int mi = 0; mi < 4; ++mi)
                a[mi] = *reinterpret_cast<const bf16x8*>(
                    ac + ((((wm*64 + mi*16 + lrow) << 7) + (kk << 6) + (q << 4)) ^ xorv));
#pragma unroll
            for (int ni = 0; ni < 2; ++ni)
                b[ni] = *reinterpret_cast<const bf16x8*>(
                    bc + ((((wn*32 + ni*16 + lrow) << 7) + (kk << 6) + (q << 4)) ^ xorv));
#pragma unroll
            for (int mi = 0; mi < 4; ++mi)
#pragma unroll
                for (int ni = 0; ni < 2; ++ni)
                    acc[mi][ni] = __builtin_amdgcn_mfma_f32_16x16x32_bf16(a[mi], b[ni], acc[mi][ni], 0, 0, 0);
        }
    };

    // ---- pipelined K-loop (24 steps) ----
    STAGE(buf0, 0);
    vmbar();
    int cur = 0;
    for (int ks = 0; ks < 24; ++ks) {
        short* curb = cur ? buf1 : buf0;
        short* nxtb = cur ? buf0 : buf1;
        if (ks < 23) STAGE(nxtb, ks + 1);   // latency hides under COMPUTE (+TLP)
        COMPUTE(curb);
        vmbar();                            // next buffer ready; cur fully read
        cur ^= 1;
    }

    // ---- epilogue: recombine gates via LDS (aliases smem), cell update ----
    __syncthreads();
    float* Ls = (float*)smem;               // 4 planes x 1089 floats (64 rows x 17)
    const int jl = tid & 15;                // local j (16 per block)
    const int jg = bn * 16 + jl;
    float bsum[4];
#pragma unroll
    for (int gg = 0; gg < 4; ++gg) bsum[gg] = bih[gg * NH + jg] + bhh[gg * NH + jg];
    const int mgrp = tid >> 4;              // 0..15

#pragma unroll
    for (int pass = 0; pass < 2; ++pass) {
        __syncthreads();
        if (wm == pass) {
            // frag: col nloc = wn*32+ni*16+lrow; row mb = mi*16+q*4+r
#pragma unroll
            for (int ni = 0; ni < 2; ++ni) {
                const int nloc = wn * 32 + ni * 16 + lrow;
                const int gg = nloc & 3;
                const int jj = nloc >> 2;          // 0..15
#pragma unroll
                for (int mi = 0; mi < 4; ++mi) {
                    const int mb = mi * 16 + q * 4;
                    f32x4 v = acc[mi][ni];
#pragma unroll
                    for (int r = 0; r < 4; ++r)
                        Ls[gg * 1089 + (mb + r) * 17 + jj] = v[r];
                }
            }
        }
        __syncthreads();
        // update 64 rows of this pass: each thread 4 rows at its j
#pragma unroll
        for (int mm = 0; mm < 4; ++mm) {
            const int ml = mgrp * 4 + mm;               // 0..63
            const int mg = bm * 128 + pass * 64 + ml;
            float gi = Ls[0 * 1089 + ml * 17 + jl] + bsum[0];
            float gf = Ls[1 * 1089 + ml * 17 + jl] + bsum[1];
            float gG = Ls[2 * 1089 + ml * 17 + jl] + bsum[2];
            float go = Ls[3 * 1089 + ml * 17 + jl] + bsum[3];
            const size_t ix = (size_t)mg * NH + jg;
            float cn = sigm(gf) * c[ix] + sigm(gi) * tanhf(gG);
            float hn = sigm(go) * tanhf(cn);
            c[ix] = cn;
            __hip_bfloat16 hb = __float2bfloat16(hn);
            h_nxt[ix] = *reinterpret_cast<unsigned short*>(&hb);
            if (cap_len[mg] == t + 1) h_last[ix] = hn;
        }
    }

    // ---- commit x prefetch ----
    if (do_gather) {
        uint2 o;
        o.x = pack_bf16(xg.x, xg.y);
        o.y = pack_bf16(xg.z, xg.w);
        *reinterpret_cast<uint2*>(x_nxt + (size_t)gxm * NE + gxe) = o;
    }
}

// ---------------------------------------------------------------------------
extern "C" void kernel_launch(void* const* d_in, const int* in_sizes, int n_in,
                              void* d_out, int out_size, void* d_ws, size_t ws_size,
                              hipStream_t stream) {
    const int* cap      = (const int*)d_in[0];
    const int* cap_len  = (const int*)d_in[1];
    const float* feat   = (const float*)d_in[2];
    const float* embed  = (const float*)d_in[3];
    const float* W_ih   = (const float*)d_in[4];
    const float* W_hh   = (const float*)d_in[5];
    const float* b_ih   = (const float*)d_in[6];
    const float* b_hh   = (const float*)d_in[7];
    const float* v_ih0  = (const float*)d_in[8];
    const float* g_ih0  = (const float*)d_in[9];
    const float* b_ih0  = (const float*)d_in[10];
    const float* v_ic0  = (const float*)d_in[11];
    const float* g_ic0  = (const float*)d_in[12];
    const float* b_ic0  = (const float*)d_in[13];
    const float* v_mu   = (const float*)d_in[14];
    const float* g_mu   = (const float*)d_in[15];
    const float* b_mu   = (const float*)d_in[16];
    const float* v_s2   = (const float*)d_in[17];
    const float* g_s2   = (const float*)d_in[18];
    const float* b_s2   = (const float*)d_in[19];
    float* out = (float*)d_out;

    // workspace (~26.6 MB)
    float* ws = (float*)d_ws;
    float* c       = ws;                                 // NB*NH
    float* h_last  = c + (size_t)NB * NH;                // NB*NH
    float* sc_ih0  = h_last + (size_t)NB * NH;           // NH
    float* sc_ic0  = sc_ih0 + NH;                        // NH
    float* sc_mu   = sc_ic0 + NH;                        // NL
    float* sc_s2   = sc_mu + NL;                         // NL
    float* fend    = sc_s2 + NL + 64;
    unsigned short* Wcat = (unsigned short*)fend;        // NG*NK
    unsigned short* h_b0 = Wcat + (size_t)NG * NK;       // NB*NH
    unsigned short* h_b1 = h_b0 + (size_t)NB * NH;       // NB*NH
    unsigned short* x_b0 = h_b1 + (size_t)NB * NH;       // NB*NE
    unsigned short* x_b1 = x_b0 + (size_t)NB * NE;       // NB*NE

    dim3 blk(256);

    k_rowscale<<<NH, blk, 0, stream>>>(v_ih0, g_ih0, sc_ih0, NA);
    k_rowscale<<<NH, blk, 0, stream>>>(v_ic0, g_ic0, sc_ic0, NA);
    k_rowscale<<<NL, blk, 0, stream>>>(v_mu, g_mu, sc_mu, NH);
    k_rowscale<<<NL, blk, 0, stream>>>(v_s2, g_s2, sc_s2, NH);

    k_build_wcat<<<(NG * NK / 8 + 255) / 256, blk, 0, stream>>>(W_ih, W_hh, Wcat);
    k_gather_x0<<<(NB * NE / 8 + 255) / 256, blk, 0, stream>>>(cap, embed, x_b0);

    // init: h0 (bf16 out) | c0 (fp32 out), 64x64 tiles -> 512 blocks, K=2048
    k_gemm_wn<<<dim3(32, 16), blk, 0, stream>>>(
        feat, NA, NA,
        v_ih0, sc_ih0, b_ih0, nullptr, h_b0, NH,
        v_ic0, sc_ic0, b_ic0, c, nullptr, NH, 16);

    unsigned short* hbuf[2] = {h_b0, h_b1};
    unsigned short* xbuf[2] = {x_b0, x_b1};
    for (int t = 0; t < NT; ++t) {
        k_lstm_fused<<<dim3(512), blk, 0, stream>>>(
            xbuf[t & 1], hbuf[t & 1], hbuf[(t + 1) & 1], xbuf[(t + 1) & 1],
            Wcat, b_ih, b_hh, c, h_last, cap, cap_len, embed,
            t, (t + 1 < NT) ? 1 : 0);
    }

    // heads: mu | sigma2, 64x64 tiles -> 128 blocks, K=1024
    k_gemm_wn<<<dim3(8, 16), blk, 0, stream>>>(
        h_last, NH, NH,
        v_mu, sc_mu, b_mu, out, nullptr, NL,
        v_s2, sc_s2, b_s2, out + (size_t)NB * NL, nullptr, NL, 4);
}